// Round 1
// baseline (236.567 us; speedup 1.0000x reference)
//
#include <hip/hip_runtime.h>

typedef _Float16 f16;
typedef _Float16 f16x4 __attribute__((ext_vector_type(4)));
typedef _Float16 f16x8 __attribute__((ext_vector_type(8)));
typedef float f32x4 __attribute__((ext_vector_type(4)));

#define BM 128
#define BN 128
#define BK 32
#define LDP 40  // LDS row stride in halves: 80B -> 16B-aligned rows, <=2-way bank conflict (free)

__device__ __forceinline__ float soft1(float a, float thr, float w, float s) {
    return copysignf(fmaxf(a - thr, 0.0f), w) * s;
}

// 2nd-smallest of 4 |values| via min/max network
__device__ __forceinline__ float thr4(float a0, float a1, float a2, float a3) {
    float lo01 = fminf(a0, a1), hi01 = fmaxf(a0, a1);
    float lo23 = fminf(a2, a3), hi23 = fmaxf(a2, a3);
    return fminf(fmaxf(lo01, lo23), fminf(hi01, hi23));
}

// W: [D][R] fp32. soft-threshold 2:4 along R. Output Bt = win_s^T: [R][D] f16.
__global__ __launch_bounds__(256) void sparsify_in_kernel(
    const float* __restrict__ W, f16* __restrict__ Bt,
    const float* __restrict__ scale_p, int D, int R)
{
    int t = blockIdx.x * 256 + threadIdx.x;  // t = d * (R/4) + rg
    int RG = R >> 2;
    if (t >= D * RG) return;
    int d = t / RG, rg = t - d * RG;
    float s = *scale_p;
    float4 w = *reinterpret_cast<const float4*>(W + (size_t)d * R + rg * 4);
    float a0 = fabsf(w.x), a1 = fabsf(w.y), a2 = fabsf(w.z), a3 = fabsf(w.w);
    float thr = thr4(a0, a1, a2, a3);
    size_t base = (size_t)(rg * 4) * D + d;
    Bt[base]              = (f16)soft1(a0, thr, w.x, s);
    Bt[base + D]          = (f16)soft1(a1, thr, w.y, s);
    Bt[base + 2 * (size_t)D] = (f16)soft1(a2, thr, w.z, s);
    Bt[base + 3 * (size_t)D] = (f16)soft1(a3, thr, w.w, s);
}

// W: [D][R] fp32 (= weight_out). wout_s = soft24(W^T) [R][D], groups of 4 along D.
// Output Bt = wout_s^T : [D][R] f16. Note Bt[(4dg+i)*R + r] uses same index as W reads.
__global__ __launch_bounds__(256) void sparsify_out_kernel(
    const float* __restrict__ W, f16* __restrict__ Bt,
    const float* __restrict__ scale_p, int D, int R)
{
    int t = blockIdx.x * 256 + threadIdx.x;  // t = dg * R + r
    if (t >= (D >> 2) * R) return;
    int dg = t / R, r = t - dg * R;
    float s = *scale_p;
    size_t i0 = (size_t)(dg * 4) * R + r;
    float w0 = W[i0], w1 = W[i0 + R], w2 = W[i0 + 2 * (size_t)R], w3 = W[i0 + 3 * (size_t)R];
    float a0 = fabsf(w0), a1 = fabsf(w1), a2 = fabsf(w2), a3 = fabsf(w3);
    float thr = thr4(a0, a1, a2, a3);
    Bt[i0]                  = (f16)soft1(a0, thr, w0, s);
    Bt[i0 + R]              = (f16)soft1(a1, thr, w1, s);
    Bt[i0 + 2 * (size_t)R]  = (f16)soft1(a2, thr, w2, s);
    Bt[i0 + 3 * (size_t)R]  = (f16)soft1(a3, thr, w3, s);
}

// C[M][N] = A[M][K] (fp32 or f16, cast to f16) @ Bt[N][K]^T (f16), fp32 accum.
// OT = f16 (store h) or float (+bias).
template <typename AT, typename OT, bool BIAS>
__global__ __launch_bounds__(256) void gemm_bt(
    const AT* __restrict__ A, const f16* __restrict__ Bt, OT* __restrict__ C,
    const float* __restrict__ bias, int M, int N, int K)
{
    __shared__ f16 As[BM][LDP];
    __shared__ f16 Bs[BN][LDP];

    const int tid  = threadIdx.x;
    const int lane = tid & 63;
    const int w    = tid >> 6;       // wave 0..3
    const int wm   = w & 1;          // 2x2 wave grid over 128x128
    const int wn   = w >> 1;
    const int l16  = lane & 15;
    const int quad = lane >> 4;
    const int bm = blockIdx.y * BM;
    const int bn = blockIdx.x * BN;

    f32x4 acc[4][4] = {};

    for (int k0 = 0; k0 < K; k0 += BK) {
        // ---- stage A tile: 128 rows x 32 halves ----
        if constexpr (sizeof(AT) == 4) {
            // fp32 A: 128x32 floats = 1024 float4; 4 per thread
            int c4 = tid & 7;              // float4 index within row (8 per row)
            int r0 = (tid >> 3) << 2;      // 4 consecutive rows
#pragma unroll
            for (int i = 0; i < 4; ++i) {
                int row = r0 + i;
                float4 v = *reinterpret_cast<const float4*>(
                    A + (size_t)(bm + row) * K + k0 + c4 * 4);
                f16x4 hv = {(f16)v.x, (f16)v.y, (f16)v.z, (f16)v.w};
                *reinterpret_cast<f16x4*>(&As[row][c4 * 4]) = hv;
            }
        } else {
            // f16 A: 128x32 halves = 512 x 16B; 2 per thread
            int c8 = tid & 3;              // 8-half chunk within row (4 per row)
            int r0 = tid >> 2;             // [0,64)
#pragma unroll
            for (int i = 0; i < 2; ++i) {
                int row = r0 + i * 64;
                int4 v = *reinterpret_cast<const int4*>(
                    (const f16*)A + (size_t)(bm + row) * K + k0 + c8 * 8);
                *reinterpret_cast<int4*>(&As[row][c8 * 8]) = v;
            }
        }
        // ---- stage B tile (always f16): Bt rows are N, cols are K ----
        {
            int c8 = tid & 3;
            int r0 = tid >> 2;
#pragma unroll
            for (int i = 0; i < 2; ++i) {
                int row = r0 + i * 64;
                int4 v = *reinterpret_cast<const int4*>(
                    Bt + (size_t)(bn + row) * K + k0 + c8 * 8);
                *reinterpret_cast<int4*>(&Bs[row][c8 * 8]) = v;
            }
        }
        __syncthreads();

        // ---- fragments + MFMA: one 16x16x32 consumes the whole BK=32 ----
        f16x8 af[4], bf[4];
#pragma unroll
        for (int m = 0; m < 4; ++m)
            af[m] = *reinterpret_cast<const f16x8*>(&As[wm * 64 + m * 16 + l16][quad * 8]);
#pragma unroll
        for (int n = 0; n < 4; ++n)
            bf[n] = *reinterpret_cast<const f16x8*>(&Bs[wn * 64 + n * 16 + l16][quad * 8]);
#pragma unroll
        for (int m = 0; m < 4; ++m)
#pragma unroll
            for (int n = 0; n < 4; ++n)
                acc[m][n] = __builtin_amdgcn_mfma_f32_16x16x32_f16(af[m], bf[n], acc[m][n], 0, 0, 0);
        __syncthreads();
    }

    // ---- epilogue: C/D layout row = quad*4 + r, col = lane&15 ----
#pragma unroll
    for (int m = 0; m < 4; ++m) {
        int row_base = bm + wm * 64 + m * 16 + quad * 4;
#pragma unroll
        for (int n = 0; n < 4; ++n) {
            int col = bn + wn * 64 + n * 16 + l16;
            float b = BIAS ? bias[col] : 0.0f;
#pragma unroll
            for (int r = 0; r < 4; ++r) {
                float v = acc[m][n][r];
                size_t idx = (size_t)(row_base + r) * N + col;
                if constexpr (BIAS) C[idx] = (OT)(v + b);
                else                C[idx] = (OT)v;
            }
        }
    }
}

extern "C" void kernel_launch(void* const* d_in, const int* in_sizes, int n_in,
                              void* d_out, int out_size, void* d_ws, size_t ws_size,
                              hipStream_t stream)
{
    const float* x      = (const float*)d_in[0];
    const float* w_in   = (const float*)d_in[1];
    const float* w_out  = (const float*)d_in[2];
    const float* bias   = (const float*)d_in[3];
    const float* sc_in  = (const float*)d_in[4];
    const float* sc_out = (const float*)d_in[5];

    const int D = in_sizes[3];            // 2048
    const int R = in_sizes[1] / D;        // 512
    const int M = in_sizes[0] / D;        // 8192 (B*S)

    f16* winT  = (f16*)d_ws;                      // [R][D] = win_s^T
    f16* woutT = winT + (size_t)R * D;            // [D][R] = wout_s^T
    f16* h     = woutT + (size_t)D * R;           // [M][R] f16
    float* out = (float*)d_out;

    int n1 = D * (R / 4);
    sparsify_in_kernel<<<(n1 + 255) / 256, 256, 0, stream>>>(w_in, winT, sc_in, D, R);
    int n2 = (D / 4) * R;
    sparsify_out_kernel<<<(n2 + 255) / 256, 256, 0, stream>>>(w_out, woutT, sc_out, D, R);

    gemm_bt<float, f16, false><<<dim3(R / BN, M / BM), 256, 0, stream>>>(
        x, winT, h, nullptr, M, R, D);
    gemm_bt<f16, float, true><<<dim3(D / BN, M / BM), 256, 0, stream>>>(
        h, woutT, out, bias, M, D, R);
}

// Round 2
// 211.284 us; speedup vs baseline: 1.1197x; 1.1197x over previous
//
#include <hip/hip_runtime.h>

typedef _Float16 f16;
typedef _Float16 f16x8 __attribute__((ext_vector_type(8)));
typedef float f32x4 __attribute__((ext_vector_type(4)));

#define BM 128
#define BN 128
#define BK 32

// Async global->LDS, 16B per lane. LDS dest is wave-uniform base; HW writes
// lane i's 16B at base + i*16 (so the LDS tile must be unpadded/contiguous
// in lane order).
__device__ __forceinline__ void g2l16(const f16* g, f16* l) {
    __builtin_amdgcn_global_load_lds(
        (const __attribute__((address_space(1))) void*)g,
        (__attribute__((address_space(3))) void*)l, 16, 0, 0);
}

__device__ __forceinline__ float soft1(float a, float thr, float w, float s) {
    return copysignf(fmaxf(a - thr, 0.0f), w) * s;
}

__device__ __forceinline__ float thr4(float a0, float a1, float a2, float a3) {
    float lo01 = fminf(a0, a1), hi01 = fmaxf(a0, a1);
    float lo23 = fminf(a2, a3), hi23 = fmaxf(a2, a3);
    return fminf(fmaxf(lo01, lo23), fminf(hi01, hi23));
}

// x fp32 -> f16 (RTE), vectorized 8 elems/thread/iter
__global__ __launch_bounds__(256) void cast_kernel(
    const float* __restrict__ in, f16* __restrict__ out, int n8)
{
    int i = blockIdx.x * 256 + threadIdx.x;
    int stride = gridDim.x * 256;
    for (; i < n8; i += stride) {
        float4 a = reinterpret_cast<const float4*>(in)[2 * i];
        float4 b = reinterpret_cast<const float4*>(in)[2 * i + 1];
        f16x8 o = {(f16)a.x, (f16)a.y, (f16)a.z, (f16)a.w,
                   (f16)b.x, (f16)b.y, (f16)b.z, (f16)b.w};
        reinterpret_cast<f16x8*>(out)[i] = o;
    }
}

// W: [D][R] fp32, 2:4 along R. Output Bt = win_s^T: [R][D] f16.
// t = rg*D + d so the 4 strided writes are coalesced across threads.
__global__ __launch_bounds__(256) void sparsify_in_kernel(
    const float* __restrict__ W, f16* __restrict__ Bt,
    const float* __restrict__ scale_p, int D, int R)
{
    int t = blockIdx.x * 256 + threadIdx.x;
    int RG = R >> 2;
    if (t >= RG * D) return;
    int rg = t / D, d = t - rg * D;
    float s = *scale_p;
    float4 w = *reinterpret_cast<const float4*>(W + (size_t)d * R + rg * 4);
    float a0 = fabsf(w.x), a1 = fabsf(w.y), a2 = fabsf(w.z), a3 = fabsf(w.w);
    float thr = thr4(a0, a1, a2, a3);
    size_t base = (size_t)(rg * 4) * D + d;
    Bt[base]                 = (f16)soft1(a0, thr, w.x, s);
    Bt[base + D]             = (f16)soft1(a1, thr, w.y, s);
    Bt[base + 2 * (size_t)D] = (f16)soft1(a2, thr, w.z, s);
    Bt[base + 3 * (size_t)D] = (f16)soft1(a3, thr, w.w, s);
}

// W: [D][R] fp32 (= weight_out). wout_s = soft24(W^T), groups of 4 along D.
// Output Bt = wout_s^T : [D][R] f16 — same indices as the reads (coalesced).
__global__ __launch_bounds__(256) void sparsify_out_kernel(
    const float* __restrict__ W, f16* __restrict__ Bt,
    const float* __restrict__ scale_p, int D, int R)
{
    int t = blockIdx.x * 256 + threadIdx.x;
    if (t >= (D >> 2) * R) return;
    int dg = t / R, r = t - dg * R;
    float s = *scale_p;
    size_t i0 = (size_t)(dg * 4) * R + r;
    float w0 = W[i0], w1 = W[i0 + R], w2 = W[i0 + 2 * (size_t)R], w3 = W[i0 + 3 * (size_t)R];
    float a0 = fabsf(w0), a1 = fabsf(w1), a2 = fabsf(w2), a3 = fabsf(w3);
    float thr = thr4(a0, a1, a2, a3);
    Bt[i0]                 = (f16)soft1(a0, thr, w0, s);
    Bt[i0 + R]             = (f16)soft1(a1, thr, w1, s);
    Bt[i0 + 2 * (size_t)R] = (f16)soft1(a2, thr, w2, s);
    Bt[i0 + 3 * (size_t)R] = (f16)soft1(a3, thr, w3, s);
}

// C[M][N] = A[M][K] f16 @ Bt[N][K]^T f16, fp32 accum. m97 structure:
// unpadded 128x32 LDS tiles, global_load_lds dwordx4 staging, 2-barrier K-loop.
template <typename OT, bool BIAS>
__global__ __launch_bounds__(256) void gemm_bt(
    const f16* __restrict__ A, const f16* __restrict__ Bt, OT* __restrict__ C,
    const float* __restrict__ bias, int M, int N, int K)
{
    __shared__ f16 As[BM * BK];   // row-major [128][32], unpadded (g2l16 layout)
    __shared__ f16 Bs[BN * BK];

    const int tid  = threadIdx.x;
    const int lane = tid & 63;
    const int w    = tid >> 6;       // wave 0..3
    const int wm   = w & 1;
    const int wn   = w >> 1;
    const int l16  = lane & 15;
    const int quad = lane >> 4;
    const int bm = blockIdx.y * BM;
    const int bn = blockIdx.x * BN;

    // staging coords: wave w stages rows [w*32, w*32+32); one g2l16 moves
    // 64 lanes x 16B = 16 rows (row = lane>>2, col8 = lane&3).
    const int srow = lane >> 2;
    const int scol = (lane & 3) * 8;
    const f16* gA = A  + (size_t)(bm + w * 32 + srow) * K + scol;
    const f16* gB = Bt + (size_t)(bn + w * 32 + srow) * K + scol;
    f16* lA = &As[(w * 32) * BK];
    f16* lB = &Bs[(w * 32) * BK];

    f32x4 acc[4][4] = {};

    for (int k0 = 0; k0 < K; k0 += BK) {
        g2l16(gA + k0,               lA);
        g2l16(gA + k0 + 16 * (size_t)K, lA + 16 * BK);
        g2l16(gB + k0,               lB);
        g2l16(gB + k0 + 16 * (size_t)K, lB + 16 * BK);
        __syncthreads();   // drains vmcnt -> staging complete

        f16x8 af[4], bf[4];
#pragma unroll
        for (int m = 0; m < 4; ++m)
            af[m] = *reinterpret_cast<const f16x8*>(&As[(wm * 64 + m * 16 + l16) * BK + quad * 8]);
#pragma unroll
        for (int n = 0; n < 4; ++n)
            bf[n] = *reinterpret_cast<const f16x8*>(&Bs[(wn * 64 + n * 16 + l16) * BK + quad * 8]);
#pragma unroll
        for (int m = 0; m < 4; ++m)
#pragma unroll
            for (int n = 0; n < 4; ++n)
                acc[m][n] = __builtin_amdgcn_mfma_f32_16x16x32_f16(af[m], bf[n], acc[m][n], 0, 0, 0);
        __syncthreads();   // frags consumed before next stage overwrites
    }

    // epilogue: C/D layout row = quad*4 + r, col = lane&15
#pragma unroll
    for (int m = 0; m < 4; ++m) {
        int row_base = bm + wm * 64 + m * 16 + quad * 4;
#pragma unroll
        for (int n = 0; n < 4; ++n) {
            int col = bn + wn * 64 + n * 16 + l16;
            float b = BIAS ? bias[col] : 0.0f;
#pragma unroll
            for (int r = 0; r < 4; ++r) {
                float v = acc[m][n][r];
                size_t idx = (size_t)(row_base + r) * N + col;
                if constexpr (BIAS) C[idx] = (OT)(v + b);
                else                C[idx] = (OT)v;
            }
        }
    }
}

extern "C" void kernel_launch(void* const* d_in, const int* in_sizes, int n_in,
                              void* d_out, int out_size, void* d_ws, size_t ws_size,
                              hipStream_t stream)
{
    const float* x      = (const float*)d_in[0];
    const float* w_in   = (const float*)d_in[1];
    const float* w_out  = (const float*)d_in[2];
    const float* bias   = (const float*)d_in[3];
    const float* sc_in  = (const float*)d_in[4];
    const float* sc_out = (const float*)d_in[5];

    const int D = in_sizes[3];            // 2048
    const int R = in_sizes[1] / D;        // 512
    const int M = in_sizes[0] / D;        // 8192 (B*S)

    f16* winT  = (f16*)d_ws;                      // [R][D]
    f16* woutT = winT + (size_t)R * D;            // [D][R]
    f16* h     = woutT + (size_t)D * R;           // [M][R]
    f16* xh    = h + (size_t)M * R;               // [M][D]
    float* out = (float*)d_out;

    cast_kernel<<<2048, 256, 0, stream>>>(x, xh, M * D / 8);
    sparsify_in_kernel<<<(D * (R / 4) + 255) / 256, 256, 0, stream>>>(w_in, winT, sc_in, D, R);
    sparsify_out_kernel<<<((D / 4) * R + 255) / 256, 256, 0, stream>>>(w_out, woutT, sc_out, D, R);

    gemm_bt<f16, false><<<dim3(R / BN, M / BM), 256, 0, stream>>>(
        xh, winT, h, nullptr, M, R, D);
    gemm_bt<float, true><<<dim3(D / BN, M / BM), 256, 0, stream>>>(
        h, woutT, out, bias, M, D, R);
}

// Round 3
// 198.822 us; speedup vs baseline: 1.1898x; 1.0627x over previous
//
#include <hip/hip_runtime.h>

typedef _Float16 f16;
typedef _Float16 f16x8 __attribute__((ext_vector_type(8)));
typedef float f32x4 __attribute__((ext_vector_type(4)));

#define BM 128
#define BK 32

// Async global->LDS, 16B per lane: lane i's 16B lands at base + i*16.
__device__ __forceinline__ void g2l16(const f16* g, f16* l) {
    __builtin_amdgcn_global_load_lds(
        (const __attribute__((address_space(1))) void*)g,
        (__attribute__((address_space(3))) void*)l, 16, 0, 0);
}

__device__ __forceinline__ float soft1(float a, float thr, float w, float s) {
    return copysignf(fmaxf(a - thr, 0.0f), w) * s;
}

__device__ __forceinline__ float thr4(float a0, float a1, float a2, float a3) {
    float lo01 = fminf(a0, a1), hi01 = fmaxf(a0, a1);
    float lo23 = fminf(a2, a3), hi23 = fmaxf(a2, a3);
    return fminf(fmaxf(lo01, lo23), fminf(hi01, hi23));
}

// One launch: [0, nCastB)           -> cast x fp32 -> f16
//             [nCastB, +nSpInB)     -> sparsify w_in   (2:4 along R), out winT  [R][D]
//             [.., +nSpOutB)        -> sparsify w_out^T (2:4 along D), out woutT [D][R]
__global__ __launch_bounds__(256) void prep_kernel(
    const float* __restrict__ x, f16* __restrict__ xh, int n8,
    const float* __restrict__ Wi, f16* __restrict__ winT, const float* __restrict__ sci,
    const float* __restrict__ Wo, f16* __restrict__ woutT, const float* __restrict__ sco,
    int D, int R, int nCastB, int nSpInB)
{
    int b = blockIdx.x;
    int tid = threadIdx.x;
    if (b < nCastB) {
        int i = b * 256 + tid;
        if (i < n8) {
            float4 a = reinterpret_cast<const float4*>(x)[2 * i];
            float4 c = reinterpret_cast<const float4*>(x)[2 * i + 1];
            f16x8 o = {(f16)a.x, (f16)a.y, (f16)a.z, (f16)a.w,
                       (f16)c.x, (f16)c.y, (f16)c.z, (f16)c.w};
            reinterpret_cast<f16x8*>(xh)[i] = o;
        }
    } else if (b < nCastB + nSpInB) {
        int t = (b - nCastB) * 256 + tid;   // t = rg*D + d (coalesced writes)
        int RG = R >> 2;
        if (t >= RG * D) return;
        int rg = t / D, d = t - rg * D;
        float s = *sci;
        float4 w = *reinterpret_cast<const float4*>(Wi + (size_t)d * R + rg * 4);
        float a0 = fabsf(w.x), a1 = fabsf(w.y), a2 = fabsf(w.z), a3 = fabsf(w.w);
        float thr = thr4(a0, a1, a2, a3);
        size_t base = (size_t)(rg * 4) * D + d;
        winT[base]                 = (f16)soft1(a0, thr, w.x, s);
        winT[base + D]             = (f16)soft1(a1, thr, w.y, s);
        winT[base + 2 * (size_t)D] = (f16)soft1(a2, thr, w.z, s);
        winT[base + 3 * (size_t)D] = (f16)soft1(a3, thr, w.w, s);
    } else {
        int t = (b - nCastB - nSpInB) * 256 + tid;  // t = dg*R + r
        if (t >= (D >> 2) * R) return;
        int dg = t / R, r = t - dg * R;
        float s = *sco;
        size_t i0 = (size_t)(dg * 4) * R + r;
        float w0 = Wo[i0], w1 = Wo[i0 + R], w2 = Wo[i0 + 2 * (size_t)R], w3 = Wo[i0 + 3 * (size_t)R];
        float a0 = fabsf(w0), a1 = fabsf(w1), a2 = fabsf(w2), a3 = fabsf(w3);
        float thr = thr4(a0, a1, a2, a3);
        woutT[i0]                 = (f16)soft1(a0, thr, w0, s);
        woutT[i0 + R]             = (f16)soft1(a1, thr, w1, s);
        woutT[i0 + 2 * (size_t)R] = (f16)soft1(a2, thr, w2, s);
        woutT[i0 + 3 * (size_t)R] = (f16)soft1(a3, thr, w3, s);
    }
}

// C[M][N] = A[M][K] f16 @ Bt[N][K]^T f16, fp32 accum. m97 structure:
// unpadded [rows][32] LDS tiles, global_load_lds dwordx4 staging, 2-barrier K-loop.
// TBN = 128 (wave tile 64x64, acc 4x4) or 64 (wave tile 64x32, acc 4x2).
template <int TBN, typename OT, bool BIAS>
__global__ __launch_bounds__(256) void gemm_bt(
    const f16* __restrict__ A, const f16* __restrict__ Bt, OT* __restrict__ C,
    const float* __restrict__ bias, int M, int N, int K)
{
    constexpr int NF = TBN / 32;   // B-fragments per wave
    constexpr int HN = TBN / 2;    // per-wave N span
    __shared__ f16 As[BM * BK];
    __shared__ f16 Bs[TBN * BK];

    const int tid  = threadIdx.x;
    const int lane = tid & 63;
    const int w    = tid >> 6;
    const int wm   = w & 1;
    const int wn   = w >> 1;
    const int l16  = lane & 15;
    const int quad = lane >> 4;
    const int bm = blockIdx.y * BM;
    const int bn = blockIdx.x * TBN;

    // one g2l16 covers 16 rows of 32 halves: row = lane>>2, col = (lane&3)*8
    const int srow = lane >> 2;
    const int scol = (lane & 3) * 8;
    const f16* gA = A  + (size_t)(bm + w * 32 + srow) * K + scol;
    const f16* gB = Bt + (size_t)(bn + w * (TBN / 4) + srow) * K + scol;
    f16* lA = &As[(w * 32) * BK];
    f16* lB = &Bs[(w * (TBN / 4)) * BK];

    f32x4 acc[4][NF] = {};

    for (int k0 = 0; k0 < K; k0 += BK) {
        g2l16(gA + k0,                  lA);
        g2l16(gA + k0 + 16 * (size_t)K, lA + 16 * BK);
#pragma unroll
        for (int i = 0; i < TBN / 64; ++i)
            g2l16(gB + k0 + i * 16 * (size_t)K, lB + i * 16 * BK);
        __syncthreads();

        f16x8 af[4], bf[NF];
#pragma unroll
        for (int m = 0; m < 4; ++m)
            af[m] = *reinterpret_cast<const f16x8*>(&As[(wm * 64 + m * 16 + l16) * BK + quad * 8]);
#pragma unroll
        for (int n = 0; n < NF; ++n)
            bf[n] = *reinterpret_cast<const f16x8*>(&Bs[(wn * HN + n * 16 + l16) * BK + quad * 8]);
#pragma unroll
        for (int m = 0; m < 4; ++m)
#pragma unroll
            for (int n = 0; n < NF; ++n)
                acc[m][n] = __builtin_amdgcn_mfma_f32_16x16x32_f16(af[m], bf[n], acc[m][n], 0, 0, 0);
        __syncthreads();
    }

    // epilogue: C/D layout row = quad*4 + r, col = lane&15
#pragma unroll
    for (int m = 0; m < 4; ++m) {
        int row_base = bm + wm * 64 + m * 16 + quad * 4;
#pragma unroll
        for (int n = 0; n < NF; ++n) {
            int col = bn + wn * HN + n * 16 + l16;
            float b = BIAS ? bias[col] : 0.0f;
#pragma unroll
            for (int r = 0; r < 4; ++r) {
                float v = acc[m][n][r];
                size_t idx = (size_t)(row_base + r) * N + col;
                if constexpr (BIAS) C[idx] = (OT)(v + b);
                else                C[idx] = (OT)v;
            }
        }
    }
}

extern "C" void kernel_launch(void* const* d_in, const int* in_sizes, int n_in,
                              void* d_out, int out_size, void* d_ws, size_t ws_size,
                              hipStream_t stream)
{
    const float* x      = (const float*)d_in[0];
    const float* w_in   = (const float*)d_in[1];
    const float* w_out  = (const float*)d_in[2];
    const float* bias   = (const float*)d_in[3];
    const float* sc_in  = (const float*)d_in[4];
    const float* sc_out = (const float*)d_in[5];

    const int D = in_sizes[3];            // 2048
    const int R = in_sizes[1] / D;        // 512
    const int M = in_sizes[0] / D;        // 8192 (B*S)

    f16* winT  = (f16*)d_ws;                      // [R][D]
    f16* woutT = winT + (size_t)R * D;            // [D][R]
    f16* h     = woutT + (size_t)D * R;           // [M][R]
    f16* xh    = h + (size_t)M * R;               // [M][D]
    float* out = (float*)d_out;

    const int n8 = M * D / 8;
    const int nCastB  = (n8 + 255) / 256;
    const int nSpInB  = ((R / 4) * D + 255) / 256;
    const int nSpOutB = ((D / 4) * R + 255) / 256;
    prep_kernel<<<nCastB + nSpInB + nSpOutB, 256, 0, stream>>>(
        x, xh, n8, w_in, winT, sc_in, w_out, woutT, sc_out, D, R, nCastB, nSpInB);

    gemm_bt<64, f16, false><<<dim3(R / 64, M / BM), 256, 0, stream>>>(
        xh, winT, h, nullptr, M, R, D);
    gemm_bt<128, float, true><<<dim3(D / 128, M / BM), 256, 0, stream>>>(
        h, woutT, out, bias, M, D, R);
}

// Round 4
// 193.705 us; speedup vs baseline: 1.2213x; 1.0264x over previous
//
#include <hip/hip_runtime.h>

typedef _Float16 f16;
typedef _Float16 f16x8 __attribute__((ext_vector_type(8)));
typedef float f32x4 __attribute__((ext_vector_type(4)));

#define BK 32

// Async global->LDS, 16B per lane: lane i's 16B lands at base + i*16.
__device__ __forceinline__ void g2l16(const f16* g, f16* l) {
    __builtin_amdgcn_global_load_lds(
        (const __attribute__((address_space(1))) void*)g,
        (__attribute__((address_space(3))) void*)l, 16, 0, 0);
}

__device__ __forceinline__ float soft1(float a, float thr, float w, float s) {
    return copysignf(fmaxf(a - thr, 0.0f), w) * s;
}

__device__ __forceinline__ float thr4(float a0, float a1, float a2, float a3) {
    float lo01 = fminf(a0, a1), hi01 = fmaxf(a0, a1);
    float lo23 = fminf(a2, a3), hi23 = fmaxf(a2, a3);
    return fminf(fmaxf(lo01, lo23), fminf(hi01, hi23));
}

// One launch: [0, nCastB)        -> cast x fp32 -> f16
//             [nCastB, +nSpInB)  -> sparsify w_in   (2:4 along R), out winT  [R][D]
//             [.., +nSpOutB)     -> sparsify w_out^T (2:4 along D), out woutT [D][R]
__global__ __launch_bounds__(256) void prep_kernel(
    const float* __restrict__ x, f16* __restrict__ xh, int n8,
    const float* __restrict__ Wi, f16* __restrict__ winT, const float* __restrict__ sci,
    const float* __restrict__ Wo, f16* __restrict__ woutT, const float* __restrict__ sco,
    int D, int R, int nCastB, int nSpInB)
{
    int b = blockIdx.x;
    int tid = threadIdx.x;
    if (b < nCastB) {
        int i = b * 256 + tid;
        if (i < n8) {
            float4 a = reinterpret_cast<const float4*>(x)[2 * i];
            float4 c = reinterpret_cast<const float4*>(x)[2 * i + 1];
            f16x8 o = {(f16)a.x, (f16)a.y, (f16)a.z, (f16)a.w,
                       (f16)c.x, (f16)c.y, (f16)c.z, (f16)c.w};
            reinterpret_cast<f16x8*>(xh)[i] = o;
        }
    } else if (b < nCastB + nSpInB) {
        int t = (b - nCastB) * 256 + tid;   // t = rg*D + d (coalesced writes)
        int RG = R >> 2;
        if (t >= RG * D) return;
        int rg = t / D, d = t - rg * D;
        float s = *sci;
        float4 w = *reinterpret_cast<const float4*>(Wi + (size_t)d * R + rg * 4);
        float a0 = fabsf(w.x), a1 = fabsf(w.y), a2 = fabsf(w.z), a3 = fabsf(w.w);
        float thr = thr4(a0, a1, a2, a3);
        size_t base = (size_t)(rg * 4) * D + d;
        winT[base]                 = (f16)soft1(a0, thr, w.x, s);
        winT[base + D]             = (f16)soft1(a1, thr, w.y, s);
        winT[base + 2 * (size_t)D] = (f16)soft1(a2, thr, w.z, s);
        winT[base + 3 * (size_t)D] = (f16)soft1(a3, thr, w.w, s);
    } else {
        int t = (b - nCastB - nSpInB) * 256 + tid;  // t = dg*R + r
        if (t >= (D >> 2) * R) return;
        int dg = t / R, r = t - dg * R;
        float s = *sco;
        size_t i0 = (size_t)(dg * 4) * R + r;
        float w0 = Wo[i0], w1 = Wo[i0 + R], w2 = Wo[i0 + 2 * (size_t)R], w3 = Wo[i0 + 3 * (size_t)R];
        float a0 = fabsf(w0), a1 = fabsf(w1), a2 = fabsf(w2), a3 = fabsf(w3);
        float thr = thr4(a0, a1, a2, a3);
        woutT[i0]                 = (f16)soft1(a0, thr, w0, s);
        woutT[i0 + R]             = (f16)soft1(a1, thr, w1, s);
        woutT[i0 + 2 * (size_t)R] = (f16)soft1(a2, thr, w2, s);
        woutT[i0 + 3 * (size_t)R] = (f16)soft1(a3, thr, w3, s);
    }
}

// C[M][N] = A[M][K] f16 @ Bt[N][K]^T f16, fp32 accum.
// m97 structure, tile TBM x TBN, 4 waves in 2x2 grid (wave tile TBM/2 x TBN/2).
// Unpadded [rows][32] LDS tiles (BK=32 row stride is bank-balanced for the
// b128 fragment reads), global_load_lds dwordx4 staging, 2-barrier K-loop.
template <int TBM, int TBN, typename OT, bool BIAS>
__global__ __launch_bounds__(256) void gemm_bt(
    const f16* __restrict__ A, const f16* __restrict__ Bt, OT* __restrict__ C,
    const float* __restrict__ bias, int M, int N, int K)
{
    constexpr int MI = TBM / 32;   // A-fragments per wave
    constexpr int NF = TBN / 32;   // B-fragments per wave
    constexpr int HM = TBM / 2;    // per-wave M span
    constexpr int HN = TBN / 2;    // per-wave N span
    __shared__ f16 As[TBM * BK];
    __shared__ f16 Bs[TBN * BK];

    const int tid  = threadIdx.x;
    const int lane = tid & 63;
    const int w    = tid >> 6;
    const int wm   = w & 1;
    const int wn   = w >> 1;
    const int l16  = lane & 15;
    const int quad = lane >> 4;
    const int bm = blockIdx.y * TBM;
    const int bn = blockIdx.x * TBN;

    // one g2l16 by a full wave covers 16 rows x 32 halves:
    // row = lane>>2, col = (lane&3)*8
    const int srow = lane >> 2;
    const int scol = (lane & 3) * 8;
    const f16* gA = A  + (size_t)(bm + w * (TBM / 4) + srow) * K + scol;
    const f16* gB = Bt + (size_t)(bn + w * (TBN / 4) + srow) * K + scol;
    f16* lA = &As[(w * (TBM / 4)) * BK];
    f16* lB = &Bs[(w * (TBN / 4)) * BK];

    f32x4 acc[MI][NF] = {};

    for (int k0 = 0; k0 < K; k0 += BK) {
#pragma unroll
        for (int i = 0; i < TBM / 64; ++i)
            g2l16(gA + k0 + i * 16 * (size_t)K, lA + i * 16 * BK);
#pragma unroll
        for (int i = 0; i < TBN / 64; ++i)
            g2l16(gB + k0 + i * 16 * (size_t)K, lB + i * 16 * BK);
        __syncthreads();

        f16x8 af[MI], bf[NF];
#pragma unroll
        for (int m = 0; m < MI; ++m)
            af[m] = *reinterpret_cast<const f16x8*>(&As[(wm * HM + m * 16 + l16) * BK + quad * 8]);
#pragma unroll
        for (int n = 0; n < NF; ++n)
            bf[n] = *reinterpret_cast<const f16x8*>(&Bs[(wn * HN + n * 16 + l16) * BK + quad * 8]);
#pragma unroll
        for (int m = 0; m < MI; ++m)
#pragma unroll
            for (int n = 0; n < NF; ++n)
                acc[m][n] = __builtin_amdgcn_mfma_f32_16x16x32_f16(af[m], bf[n], acc[m][n], 0, 0, 0);
        __syncthreads();
    }

    // epilogue: C/D layout row = quad*4 + r, col = lane&15
#pragma unroll
    for (int m = 0; m < MI; ++m) {
        int row_base = bm + wm * HM + m * 16 + quad * 4;
#pragma unroll
        for (int n = 0; n < NF; ++n) {
            int col = bn + wn * HN + n * 16 + l16;
            float b = BIAS ? bias[col] : 0.0f;
#pragma unroll
            for (int r = 0; r < 4; ++r) {
                float v = acc[m][n][r];
                size_t idx = (size_t)(row_base + r) * N + col;
                if constexpr (BIAS) C[idx] = (OT)(v + b);
                else                C[idx] = (OT)v;
            }
        }
    }
}

extern "C" void kernel_launch(void* const* d_in, const int* in_sizes, int n_in,
                              void* d_out, int out_size, void* d_ws, size_t ws_size,
                              hipStream_t stream)
{
    const float* x      = (const float*)d_in[0];
    const float* w_in   = (const float*)d_in[1];
    const float* w_out  = (const float*)d_in[2];
    const float* bias   = (const float*)d_in[3];
    const float* sc_in  = (const float*)d_in[4];
    const float* sc_out = (const float*)d_in[5];

    const int D = in_sizes[3];            // 2048
    const int R = in_sizes[1] / D;        // 512
    const int M = in_sizes[0] / D;        // 8192 (B*S)

    f16* winT  = (f16*)d_ws;                      // [R][D]
    f16* woutT = winT + (size_t)R * D;            // [D][R]
    f16* h     = woutT + (size_t)D * R;           // [M][R]
    f16* xh    = h + (size_t)M * R;               // [M][D]
    float* out = (float*)d_out;

    const int n8 = M * D / 8;
    const int nCastB  = (n8 + 255) / 256;
    const int nSpInB  = ((R / 4) * D + 255) / 256;
    const int nSpOutB = ((D / 4) * R + 255) / 256;
    prep_kernel<<<nCastB + nSpInB + nSpOutB, 256, 0, stream>>>(
        x, xh, n8, w_in, winT, sc_in, w_out, woutT, sc_out, D, R, nCastB, nSpInB);

    // GEMM1: 1024 blocks = 4/CU (occupancy to overlap barrier drains)
    gemm_bt<64, 64, f16, false><<<dim3(R / 64, M / 64), 256, 0, stream>>>(
        xh, winT, h, nullptr, M, R, D);
    // GEMM2: 2048 blocks = 8/CU
    gemm_bt<64, 128, float, true><<<dim3(D / 128, M / 64), 256, 0, stream>>>(
        h, woutT, out, bias, M, D, R);
}